// Round 12
// baseline (578.988 us; speedup 1.0000x reference)
//
#include <hip/hip_runtime.h>
#include <hip/hip_bf16.h>
#include <hip/hip_cooperative_groups.h>

namespace cg = cooperative_groups;

// SGC: out = A'^2 X W^T + b, A' = D^-1/2 (A+I) D^-1/2, A_data == 1.
// Identity: A'(A'(X W^T)) = (A'^2 X) W^T -> project 128->64 FIRST, propagate 64-dim.
//   xp = is * bf16(X) bf16(W)^T;  z1 = is^2 (A+I) xp;  out = is (A+I) z1 + b
// R11 post-mortem: half-split regressed via per-launch overhead (~12us each).
// => SINGLE cooperative kernel, grid.sync() between phases (zero, bucket, csr,
// proj-MFMA, spmm1, spmm2). R10 interleaved layout (64 bf16/row). Grid 512
// blocks (2/CU co-resident; LDS 42KB -> 3/CU capacity), grid-stride phases.

#define NFEAT 128
#define NCLS  64
#define BCAP  10240    // per-bucket capacity; mean 8163, sigma ~90 -> +23 sigma
#define T1    16       // edges per thread, bucket phase (4096 edges/block-chunk)
#define XSTR  136      // proj staged row stride in bf16 elems
#define GRID  512      // 2 blocks/CU on 256 CUs

typedef __attribute__((ext_vector_type(8))) short s16x8;   // 8 bf16 = 4 VGPRs
typedef __attribute__((ext_vector_type(4))) float f32x4;   // MFMA C/D

static __device__ __forceinline__ unsigned short f2bf(float f) {
    __hip_bfloat16 h = __float2bfloat16(f);
    unsigned short u;
    __builtin_memcpy(&u, &h, 2);
    return u;
}

static __device__ __forceinline__ float bf2f(unsigned short u) {
    unsigned int w = ((unsigned int)u) << 16;
    float f;
    __builtin_memcpy(&f, &w, 4);
    return f;
}

// ---------------- fused pipeline ----------------

__global__ __launch_bounds__(256, 2)
void sgc_fused_kernel(const float* __restrict__ x, const int2* __restrict__ idx,
                      const float* __restrict__ W, const float* __restrict__ bias,
                      float* __restrict__ out,
                      int* __restrict__ bcur, int* __restrict__ bpack,
                      int* __restrict__ csr, int2* __restrict__ rowinfo,
                      unsigned short* __restrict__ xp, unsigned short* __restrict__ z1,
                      int n, int E, int nb, int nchunks, int ntiles) {
    cg::grid_group grid = cg::this_grid();
    __shared__ __align__(16) char smem[43008];   // max phase: csr = 42000 B
    int tid = threadIdx.x;
    int lane = tid & 63;

    // ---- phase 0: zero bucket cursors ----
    for (int i = blockIdx.x * 256 + tid; i < nb; i += gridDim.x * 256) bcur[i] = 0;
    grid.sync();

    // ---- phase 1: bucket split (row>>8), packed (row&255)<<24 | col ----
    {
        int*   hist   = (int*)smem;             // 1 KB
        int*   base   = (int*)(smem + 1024);    // 1 KB
        int*   packed = (int*)(smem + 2048);    // 16 KB
        short* digit  = (short*)(smem + 18432); // 8 KB
        for (int chunk = blockIdx.x; chunk < nchunks; chunk += gridDim.x) {
            hist[tid] = 0;
            __syncthreads();
            int e0 = chunk * 256 * T1;
#pragma unroll
            for (int k = 0; k < T1; ++k) {
                int e = e0 + k * 256 + tid;
                int s = k * 256 + tid;
                if (e < E) {
                    int2 rc = idx[e];
                    int d = rc.x >> 8;
                    digit[s] = (short)d;
                    packed[s] = ((rc.x & 255) << 24) | rc.y;
                    atomicAdd(&hist[d], 1);                     // LDS atomic
                } else {
                    digit[s] = -1;
                }
            }
            __syncthreads();
            {
                int c = hist[tid];
                base[tid] = (c > 0) ? atomicAdd(&bcur[tid], c) : 0;  // 1 glob atomic/digit
                hist[tid] = 0;                                       // reuse as cursor
            }
            __syncthreads();
#pragma unroll
            for (int k = 0; k < T1; ++k) {
                int s = k * 256 + tid;
                int d = digit[s];
                if (d >= 0) {
                    int r = base[d] + atomicAdd(&hist[d], 1);   // LDS atomic
                    if (r < BCAP) bpack[d * BCAP + r] = packed[s];
                }
            }
            __syncthreads();   // protect hist reuse next chunk
        }
    }
    grid.sync();

    // ---- phase 2: per-bucket CSR (rowinfo + contiguous cols) ----
    {
        int* cnt   = (int*)smem;            // 1 KB
        int* wtot  = (int*)(smem + 1024);   // 16 B
        int* stage = (int*)(smem + 1040);   // 40 KB
        int wid = tid >> 6;
        for (int b = blockIdx.x; b < nb; b += gridDim.x) {
            int m = bcur[b]; if (m > BCAP) m = BCAP;
            const int* src = bpack + b * BCAP;
            cnt[tid] = 0;
            __syncthreads();
            for (int j = tid; j < m; j += 256) {
                int p = src[j];
                stage[j] = p;
                atomicAdd(&cnt[((unsigned)p) >> 24], 1);        // LDS atomic
            }
            __syncthreads();
            int v = cnt[tid], s = v;
#pragma unroll
            for (int off = 1; off < 64; off <<= 1) {
                int t = __shfl_up(s, off, 64);
                if (lane >= off) s += t;
            }
            if (lane == 63) wtot[wid] = s;
            __syncthreads();
            int wbase = 0;
#pragma unroll
            for (int w = 0; w < 4; ++w) { int t = wtot[w]; if (w < wid) wbase += t; }
            int excl = wbase + s - v;
            int row = (b << 8) + tid;
            int csrbase = b * BCAP;
            if (row < n) rowinfo[row] = make_int2(csrbase + excl, v);
            __syncthreads();
            cnt[tid] = excl;              // reuse as write cursors
            __syncthreads();
            for (int j = tid; j < m; j += 256) {
                int p = stage[j];
                unsigned d = ((unsigned)p) >> 24;
                int r = atomicAdd(&cnt[d], 1);                  // LDS atomic
                csr[csrbase + r] = p & 0xFFFFFF;
            }
            __syncthreads();   // protect cnt reuse next bucket
        }
    }
    grid.sync();

    // ---- phase 3: projection (MFMA 16x16x32): xp = is * bf16(X) bf16(W)^T ----
    // A[m=lane&15][k=q*8+j], B[n=lane&15][k=q*8+j], D: col=lane&15, row=q*4+reg.
    {
        unsigned short* Xs = (unsigned short*)smem;             // 17 KB
        unsigned short* Ws = (unsigned short*)(smem + 17408);   // 17 KB
        int wv = tid >> 6;
        int mn = lane & 15, q = lane >> 4;
        for (int tile = blockIdx.x; tile < ntiles; tile += gridDim.x) {
            int row0 = tile * 64;
            for (int g = tid; g < 2048; g += 256) {    // 64 rows x 32 float4-granules
                int r = g >> 5, c4 = g & 31;
                int rr = row0 + r; if (rr >= n) rr = n - 1;
                float4 v = *(const float4*)&x[rr * NFEAT + 4 * c4];
                ushort4 o = { f2bf(v.x), f2bf(v.y), f2bf(v.z), f2bf(v.w) };
                *(ushort4*)&Xs[r * XSTR + 4 * c4] = o;
            }
            for (int g = tid; g < 2048; g += 256) {    // 64 cls x 32 granules
                int r = g >> 5, c4 = g & 31;
                float4 v = *(const float4*)&W[r * NFEAT + 4 * c4];
                ushort4 o = { f2bf(v.x), f2bf(v.y), f2bf(v.z), f2bf(v.w) };
                *(ushort4*)&Ws[r * XSTR + 4 * c4] = o;
            }
            __syncthreads();

            f32x4 z = { 0.0f, 0.0f, 0.0f, 0.0f };
            f32x4 acc[4] = { z, z, z, z };
            const unsigned short* xrow = &Xs[(16 * wv + mn) * XSTR];
#pragma unroll
            for (int kk = 0; kk < 4; ++kk) {
                s16x8 a = *(const s16x8*)&xrow[kk * 32 + q * 8];
#pragma unroll
                for (int t = 0; t < 4; ++t) {
                    s16x8 b = *(const s16x8*)&Ws[(16 * t + mn) * XSTR + kk * 32 + q * 8];
                    acc[t] = __builtin_amdgcn_mfma_f32_16x16x32_bf16(a, b, acc[t], 0, 0, 0);
                }
            }
#pragma unroll
            for (int r = 0; r < 4; ++r) {
                int rr = row0 + 16 * wv + 4 * q + r;
                if (rr < n) {
                    float is = rsqrtf(1.0f + (float)rowinfo[rr].y);
#pragma unroll
                    for (int t = 0; t < 4; ++t)
                        xp[rr * NCLS + 16 * t + mn] = f2bf(acc[t][r] * is);
                }
            }
            __syncthreads();   // protect Xs/Ws restage next tile
        }
    }
    grid.sync();

    // ---- phases 4/5: SpMM x2, quarter-wave pairing, wave-per-row grid-stride ----
    // lane: f = lane&15 -> feats 4f..4f+3 (ushort4), h = lane>>4 -> edge j+h.
    int h = lane >> 4, f = lane & 15;
    int gw = blockIdx.x * 4 + (tid >> 6);
    int nw = gridDim.x * 4;

#pragma unroll 1
    for (int layer = 0; layer < 2; ++layer) {
        const ushort4* src = (const ushort4*)(layer == 0 ? xp : z1);
        for (int row = gw; row < n; row += nw) {
            int2 ri = rowinfo[row];
            int m = ri.y;
            float is = rsqrtf(1.0f + (float)m);
            const int* eb = csr + ri.x;

            float4 acc = { 0.0f, 0.0f, 0.0f, 0.0f };
            if (h == 0) {                                   // self loop
                ushort4 s = src[(row << 4) + f];
                acc.x = bf2f(s.x); acc.y = bf2f(s.y); acc.z = bf2f(s.z); acc.w = bf2f(s.w);
            }

            int j = 0;
            for (; j + 32 <= m; j += 32) {                  // 8 gather insts in flight
                int c0 = eb[j + h],      c1 = eb[j + 4 + h];
                int c2 = eb[j + 8 + h],  c3 = eb[j + 12 + h];
                int c4 = eb[j + 16 + h], c5 = eb[j + 20 + h];
                int c6 = eb[j + 24 + h], c7 = eb[j + 28 + h];
                ushort4 g0 = src[(c0 << 4) + f];
                ushort4 g1 = src[(c1 << 4) + f];
                ushort4 g2 = src[(c2 << 4) + f];
                ushort4 g3 = src[(c3 << 4) + f];
                ushort4 g4 = src[(c4 << 4) + f];
                ushort4 g5 = src[(c5 << 4) + f];
                ushort4 g6 = src[(c6 << 4) + f];
                ushort4 g7 = src[(c7 << 4) + f];
                acc.x += bf2f(g0.x); acc.y += bf2f(g0.y); acc.z += bf2f(g0.z); acc.w += bf2f(g0.w);
                acc.x += bf2f(g1.x); acc.y += bf2f(g1.y); acc.z += bf2f(g1.z); acc.w += bf2f(g1.w);
                acc.x += bf2f(g2.x); acc.y += bf2f(g2.y); acc.z += bf2f(g2.z); acc.w += bf2f(g2.w);
                acc.x += bf2f(g3.x); acc.y += bf2f(g3.y); acc.z += bf2f(g3.z); acc.w += bf2f(g3.w);
                acc.x += bf2f(g4.x); acc.y += bf2f(g4.y); acc.z += bf2f(g4.z); acc.w += bf2f(g4.w);
                acc.x += bf2f(g5.x); acc.y += bf2f(g5.y); acc.z += bf2f(g5.z); acc.w += bf2f(g5.w);
                acc.x += bf2f(g6.x); acc.y += bf2f(g6.y); acc.z += bf2f(g6.z); acc.w += bf2f(g6.w);
                acc.x += bf2f(g7.x); acc.y += bf2f(g7.y); acc.z += bf2f(g7.z); acc.w += bf2f(g7.w);
            }
            for (; j + 8 <= m; j += 8) {
                int c0 = eb[j + h], c1 = eb[j + 4 + h];
                ushort4 g0 = src[(c0 << 4) + f];
                ushort4 g1 = src[(c1 << 4) + f];
                acc.x += bf2f(g0.x); acc.y += bf2f(g0.y); acc.z += bf2f(g0.z); acc.w += bf2f(g0.w);
                acc.x += bf2f(g1.x); acc.y += bf2f(g1.y); acc.z += bf2f(g1.z); acc.w += bf2f(g1.w);
            }
            for (; j < m; j += 4) {
                if (j + h < m) {
                    int c = eb[j + h];
                    ushort4 g = src[(c << 4) + f];
                    acc.x += bf2f(g.x); acc.y += bf2f(g.y); acc.z += bf2f(g.z); acc.w += bf2f(g.w);
                }
            }

            acc.x += __shfl_xor(acc.x, 16); acc.y += __shfl_xor(acc.y, 16);
            acc.z += __shfl_xor(acc.z, 16); acc.w += __shfl_xor(acc.w, 16);
            acc.x += __shfl_xor(acc.x, 32); acc.y += __shfl_xor(acc.y, 32);
            acc.z += __shfl_xor(acc.z, 32); acc.w += __shfl_xor(acc.w, 32);

            if (h == 0) {
                if (layer == 1) {
                    float4 b = *(const float4*)&bias[4 * f];
                    float4 o = { acc.x * is + b.x, acc.y * is + b.y,
                                 acc.z * is + b.z, acc.w * is + b.w };
                    ((float4*)out)[(row << 4) + f] = o;
                } else {
                    float sc = is * is;
                    ushort4 o = { f2bf(acc.x * sc), f2bf(acc.y * sc),
                                  f2bf(acc.z * sc), f2bf(acc.w * sc) };
                    ((ushort4*)z1)[(row << 4) + f] = o;
                }
            }
        }
        if (layer == 0) grid.sync();
    }
}

// ---------------- launch ----------------

extern "C" void kernel_launch(void* const* d_in, const int* in_sizes, int n_in,
                              void* d_out, int out_size, void* d_ws, size_t ws_size,
                              hipStream_t stream) {
    const float* X     = (const float*)d_in[0];
    const int2*  Aidx  = (const int2*)d_in[2];
    const float* W     = (const float*)d_in[3];
    const float* bias  = (const float*)d_in[4];
    float*       out   = (float*)d_out;

    int n = in_sizes[0] / NFEAT;   // 50000
    int E = in_sizes[1];           // 1600000
    int nb = (n + 255) >> 8;       // 196 buckets
    int nchunks = (E + 256 * T1 - 1) / (256 * T1);   // 391
    int ntiles  = (n + 63) / 64;                     // 782

    char* ws = (char*)d_ws;
    size_t o = 0;
    auto alloc = [&](size_t bytes) { void* p = ws + o; o += (bytes + 255) & ~(size_t)255; return p; };
    int*  bcur    = (int*) alloc(nb * sizeof(int));
    int*  bpack   = (int*) alloc((size_t)nb * BCAP * sizeof(int));   // 8 MB
    int*  csr     = (int*) alloc((size_t)nb * BCAP * sizeof(int));   // 8 MB
    int2* rowinfo = (int2*)alloc((size_t)n * sizeof(int2));          // 0.4 MB
    unsigned short* xp = (unsigned short*)alloc((size_t)n * NCLS * sizeof(unsigned short)); // 6.4 MB
    unsigned short* z1 = (unsigned short*)alloc((size_t)n * NCLS * sizeof(unsigned short)); // 6.4 MB

    void* args[] = { &X, &Aidx, &W, &bias, &out,
                     &bcur, &bpack, &csr, &rowinfo, &xp, &z1,
                     &n, &E, &nb, &nchunks, &ntiles };
    hipLaunchCooperativeKernel((void*)sgc_fused_kernel, dim3(GRID), dim3(256),
                               args, 0, stream);
}

// Round 13
// 193.063 us; speedup vs baseline: 2.9990x; 2.9990x over previous
//
#include <hip/hip_runtime.h>
#include <hip/hip_bf16.h>

// SGC: out = A'^2 X W^T + b, A' = D^-1/2 (A+I) D^-1/2, A_data == 1.
// Identity: A'(A'(X W^T)) = (A'^2 X) W^T -> project 128->64 FIRST, propagate 64-dim.
//   xp = is * bf16(X) bf16(W)^T;  z1 = is^2 (A+I) xp;  out = is (A+I) z1 + b
// Structure: R10's 6 separate launches (R12 cooperative fusion collapsed
// occupancy to 8 waves/CU and ran 3x slower — spmm is latency-bound and
// needs ~32 waves/CU of TLP; launch overhead is the cheaper price).
// proj change vs R10: A-fragments read DIRECTLY from global (in-register
// fp32->bf16 cvt), LDS stages only W (17 KB) — X skips the LDS round trip.

#define NFEAT 128
#define NCLS  64
#define BCAP  10240    // per-bucket capacity; mean 8163, sigma ~90 -> +23 sigma
#define T1    16       // edges per thread, pass 1 (4096 edges/block)
#define XSTR  136      // W staged row stride in bf16 elems

typedef __attribute__((ext_vector_type(8))) short s16x8;   // 8 bf16 = 4 VGPRs
typedef __attribute__((ext_vector_type(4))) float f32x4;   // MFMA C/D

static __device__ __forceinline__ unsigned short f2bf(float f) {
    __hip_bfloat16 h = __float2bfloat16(f);
    unsigned short u;
    __builtin_memcpy(&u, &h, 2);
    return u;
}

static __device__ __forceinline__ float bf2f(unsigned short u) {
    unsigned int w = ((unsigned int)u) << 16;
    float f;
    __builtin_memcpy(&f, &w, 4);
    return f;
}

// ---------------- build ----------------

__global__ void zero_kernel(int* __restrict__ bcur, int nb) {
    int i = blockIdx.x * blockDim.x + threadIdx.x;
    if (i < nb) bcur[i] = 0;
}

// pass 1: split edges into 256-row buckets, packed as (row&255)<<24 | col
__global__ __launch_bounds__(256) void bucket_kernel(const int2* __restrict__ idx,
                                                     int* __restrict__ bcur,
                                                     int* __restrict__ bpack, int E) {
    __shared__ int hist[256];
    __shared__ int base[256];
    __shared__ int packed[256 * T1];   // 16 KB
    __shared__ short digit[256 * T1];  // 8 KB
    int tid = threadIdx.x;
    for (int i = tid; i < 256; i += 256) hist[i] = 0;
    __syncthreads();

    int e0 = blockIdx.x * 256 * T1;
#pragma unroll
    for (int k = 0; k < T1; ++k) {
        int e = e0 + k * 256 + tid;
        int s = k * 256 + tid;
        if (e < E) {
            int2 rc = idx[e];
            int d = rc.x >> 8;
            digit[s] = (short)d;
            packed[s] = ((rc.x & 255) << 24) | rc.y;
            atomicAdd(&hist[d], 1);                     // LDS atomic
        } else {
            digit[s] = -1;
        }
    }
    __syncthreads();
    for (int i = tid; i < 256; i += 256) {
        int c = hist[i];
        base[i] = (c > 0) ? atomicAdd(&bcur[i], c) : 0; // 1 global atomic/digit/block
        hist[i] = 0;                                    // reuse as cursor
    }
    __syncthreads();
#pragma unroll
    for (int k = 0; k < T1; ++k) {
        int s = k * 256 + tid;
        int d = digit[s];
        if (d >= 0) {
            int r = base[d] + atomicAdd(&hist[d], 1);   // LDS atomic
            if (r < BCAP) bpack[d * BCAP + r] = packed[s];
        }
    }
}

// pass 2: one block per bucket -> rowinfo + block-contiguous CSR cols
__global__ __launch_bounds__(256) void csr_kernel(const int* __restrict__ bcur,
                                                  const int* __restrict__ bpack,
                                                  int* __restrict__ csr,
                                                  int2* __restrict__ rowinfo, int n) {
    __shared__ int cnt[256];
    __shared__ int wtot[4];
    __shared__ int stage[BCAP];        // 40 KB
    int b = blockIdx.x, tid = threadIdx.x;
    int m = bcur[b]; if (m > BCAP) m = BCAP;
    const int* src = bpack + b * BCAP;

    cnt[tid] = 0;
    __syncthreads();
    for (int j = tid; j < m; j += 256) {
        int p = src[j];
        stage[j] = p;
        atomicAdd(&cnt[((unsigned)p) >> 24], 1);        // LDS atomic
    }
    __syncthreads();

    // exclusive scan of cnt[256]
    int lane = tid & 63, wid = tid >> 6;
    int v = cnt[tid], s = v;
#pragma unroll
    for (int off = 1; off < 64; off <<= 1) {
        int t = __shfl_up(s, off, 64);
        if (lane >= off) s += t;
    }
    if (lane == 63) wtot[wid] = s;
    __syncthreads();
    int wbase = 0;
#pragma unroll
    for (int w = 0; w < 4; ++w) { int t = wtot[w]; if (w < wid) wbase += t; }
    int excl = wbase + s - v;

    int row = (b << 8) + tid;
    int csrbase = b * BCAP;
    if (row < n) rowinfo[row] = make_int2(csrbase + excl, v);
    __syncthreads();              // everyone done reading cnt as counts
    cnt[tid] = excl;              // reuse as write cursors
    __syncthreads();
    for (int j = tid; j < m; j += 256) {
        int p = stage[j];
        unsigned d = ((unsigned)p) >> 24;
        int r = atomicAdd(&cnt[d], 1);                  // LDS atomic
        csr[csrbase + r] = p & 0xFFFFFF;
    }
}

// ---------------- projection (MFMA): xp[r][c] = bf16( is_r * dot(X[r,:], W[c,:]) ) ----------------
// 64x64 tile / block, 4 waves; wave w -> rows 16w..16w+15, all 64 cls.
// A[m=lane&15][k=q*8+j] loaded DIRECTLY from global (2x float4 + in-reg cvt);
// B from LDS (W staged once, 17 KB). D: col=lane&15, row=q*4+reg.

__global__ __launch_bounds__(256) void proj_kernel(const float* __restrict__ x,
                                                   const float* __restrict__ W,
                                                   const int2* __restrict__ rowinfo,
                                                   unsigned short* __restrict__ xp, int n) {
    __shared__ unsigned short Ws[64 * XSTR];   // 17 KB
    int tid = threadIdx.x;
    int row0 = blockIdx.x * 64;

    for (int g = tid; g < 2048; g += 256) {    // 64 cls x 32 float4-granules
        int r = g >> 5, c4 = g & 31;
        float4 v = *(const float4*)&W[r * NFEAT + 4 * c4];
        ushort4 o = { f2bf(v.x), f2bf(v.y), f2bf(v.z), f2bf(v.w) };
        *(ushort4*)&Ws[r * XSTR + 4 * c4] = o;
    }
    __syncthreads();

    int wv = tid >> 6;
    int lane = tid & 63;
    int mn = lane & 15, q = lane >> 4;

    int arow = row0 + 16 * wv + mn;            // this lane's A row
    if (arow >= n) arow = n - 1;
    const float* xr = &x[(size_t)arow * NFEAT];

    f32x4 z = { 0.0f, 0.0f, 0.0f, 0.0f };
    f32x4 acc[4] = { z, z, z, z };             // 4 cls-tiles of 16

#pragma unroll
    for (int kk = 0; kk < 4; ++kk) {           // K = 4 x 32; this lane: k = kk*32+q*8..+7
        float4 a0 = *(const float4*)&xr[kk * 32 + q * 8];
        float4 a1 = *(const float4*)&xr[kk * 32 + q * 8 + 4];
        unsigned short ab[8] = { f2bf(a0.x), f2bf(a0.y), f2bf(a0.z), f2bf(a0.w),
                                 f2bf(a1.x), f2bf(a1.y), f2bf(a1.z), f2bf(a1.w) };
        s16x8 a;
        __builtin_memcpy(&a, ab, 16);
#pragma unroll
        for (int t = 0; t < 4; ++t) {
            s16x8 b = *(const s16x8*)&Ws[(16 * t + mn) * XSTR + kk * 32 + q * 8];
            acc[t] = __builtin_amdgcn_mfma_f32_16x16x32_bf16(a, b, acc[t], 0, 0, 0);
        }
    }

#pragma unroll
    for (int r = 0; r < 4; ++r) {
        int rr = row0 + 16 * wv + 4 * q + r;
        if (rr < n) {
            float is = rsqrtf(1.0f + (float)rowinfo[rr].y);
#pragma unroll
            for (int t = 0; t < 4; ++t)
                xp[rr * NCLS + 16 * t + mn] = f2bf(acc[t][r] * is);
        }
    }
}

// ---------------- SpMM: wave per row, quarter-wave pairing ----------------
// lane: f = lane&15 covers feats 4f..4f+3 (ushort4, 8B), h = lane>>4 -> edge j+h.
// 4 edges per gather inst; 8-step unroll = 32 edges in flight.
// Reduce: shfl_xor(16) + shfl_xor(32); h==0 lanes hold the row result.

template <int FINAL>
__global__ __launch_bounds__(256) void spmm_kernel(const ushort4* __restrict__ xp,
                                                   const int2* __restrict__ rowinfo,
                                                   const int* __restrict__ csr,
                                                   const float* __restrict__ bias,
                                                   void* __restrict__ yout, int n) {
    int row = blockIdx.x * 4 + (threadIdx.x >> 6);
    if (row >= n) return;
    int lane = threadIdx.x & 63;
    int h = lane >> 4, f = lane & 15;

    int2 ri = rowinfo[row];
    int m = ri.y;
    float is = rsqrtf(1.0f + (float)m);
    const int* eb = csr + ri.x;

    float4 acc = { 0.0f, 0.0f, 0.0f, 0.0f };
    if (h == 0) {                                   // self loop
        ushort4 s = xp[(row << 4) + f];
        acc.x = bf2f(s.x); acc.y = bf2f(s.y); acc.z = bf2f(s.z); acc.w = bf2f(s.w);
    }

    int j = 0;
    for (; j + 32 <= m; j += 32) {                  // 8 gather insts, 32 edges in flight
        int c0 = eb[j + h],      c1 = eb[j + 4 + h];
        int c2 = eb[j + 8 + h],  c3 = eb[j + 12 + h];
        int c4 = eb[j + 16 + h], c5 = eb[j + 20 + h];
        int c6 = eb[j + 24 + h], c7 = eb[j + 28 + h];
        ushort4 g0 = xp[(c0 << 4) + f];
        ushort4 g1 = xp[(c1 << 4) + f];
        ushort4 g2 = xp[(c2 << 4) + f];
        ushort4 g3 = xp[(c3 << 4) + f];
        ushort4 g4 = xp[(c4 << 4) + f];
        ushort4 g5 = xp[(c5 << 4) + f];
        ushort4 g6 = xp[(c6 << 4) + f];
        ushort4 g7 = xp[(c7 << 4) + f];
        acc.x += bf2f(g0.x); acc.y += bf2f(g0.y); acc.z += bf2f(g0.z); acc.w += bf2f(g0.w);
        acc.x += bf2f(g1.x); acc.y += bf2f(g1.y); acc.z += bf2f(g1.z); acc.w += bf2f(g1.w);
        acc.x += bf2f(g2.x); acc.y += bf2f(g2.y); acc.z += bf2f(g2.z); acc.w += bf2f(g2.w);
        acc.x += bf2f(g3.x); acc.y += bf2f(g3.y); acc.z += bf2f(g3.z); acc.w += bf2f(g3.w);
        acc.x += bf2f(g4.x); acc.y += bf2f(g4.y); acc.z += bf2f(g4.z); acc.w += bf2f(g4.w);
        acc.x += bf2f(g5.x); acc.y += bf2f(g5.y); acc.z += bf2f(g5.z); acc.w += bf2f(g5.w);
        acc.x += bf2f(g6.x); acc.y += bf2f(g6.y); acc.z += bf2f(g6.z); acc.w += bf2f(g6.w);
        acc.x += bf2f(g7.x); acc.y += bf2f(g7.y); acc.z += bf2f(g7.z); acc.w += bf2f(g7.w);
    }
    for (; j + 8 <= m; j += 8) {
        int c0 = eb[j + h], c1 = eb[j + 4 + h];
        ushort4 g0 = xp[(c0 << 4) + f];
        ushort4 g1 = xp[(c1 << 4) + f];
        acc.x += bf2f(g0.x); acc.y += bf2f(g0.y); acc.z += bf2f(g0.z); acc.w += bf2f(g0.w);
        acc.x += bf2f(g1.x); acc.y += bf2f(g1.y); acc.z += bf2f(g1.z); acc.w += bf2f(g1.w);
    }
    for (; j < m; j += 4) {
        if (j + h < m) {
            int c = eb[j + h];
            ushort4 g = xp[(c << 4) + f];
            acc.x += bf2f(g.x); acc.y += bf2f(g.y); acc.z += bf2f(g.z); acc.w += bf2f(g.w);
        }
    }

    acc.x += __shfl_xor(acc.x, 16); acc.y += __shfl_xor(acc.y, 16);
    acc.z += __shfl_xor(acc.z, 16); acc.w += __shfl_xor(acc.w, 16);
    acc.x += __shfl_xor(acc.x, 32); acc.y += __shfl_xor(acc.y, 32);
    acc.z += __shfl_xor(acc.z, 32); acc.w += __shfl_xor(acc.w, 32);

    if (h == 0) {
        if (FINAL) {
            float4 b = *(const float4*)&bias[4 * f];
            float4 o = { acc.x * is + b.x, acc.y * is + b.y,
                         acc.z * is + b.z, acc.w * is + b.w };
            ((float4*)yout)[(row << 4) + f] = o;
        } else {
            float sc = is * is;
            ushort4 o = { f2bf(acc.x * sc), f2bf(acc.y * sc),
                          f2bf(acc.z * sc), f2bf(acc.w * sc) };
            ((ushort4*)yout)[(row << 4) + f] = o;
        }
    }
}

// ---------------- launch ----------------

extern "C" void kernel_launch(void* const* d_in, const int* in_sizes, int n_in,
                              void* d_out, int out_size, void* d_ws, size_t ws_size,
                              hipStream_t stream) {
    const float* X     = (const float*)d_in[0];
    const int*   Aidx  = (const int*)d_in[2];
    const float* W     = (const float*)d_in[3];
    const float* bias  = (const float*)d_in[4];
    float*       out   = (float*)d_out;

    const int n = in_sizes[0] / NFEAT;   // 50000
    const int E = in_sizes[1];           // 1600000
    const int nb = (n + 255) >> 8;       // 196 buckets

    char* ws = (char*)d_ws;
    size_t o = 0;
    auto alloc = [&](size_t bytes) { void* p = ws + o; o += (bytes + 255) & ~(size_t)255; return p; };
    int*  bcur    = (int*) alloc(nb * sizeof(int));
    int*  bpack   = (int*) alloc((size_t)nb * BCAP * sizeof(int));   // 8 MB
    int*  csr     = (int*) alloc((size_t)nb * BCAP * sizeof(int));   // 8 MB
    int2* rowinfo = (int2*)alloc((size_t)n * sizeof(int2));          // 0.4 MB
    unsigned short* xp = (unsigned short*)alloc((size_t)n * NCLS * sizeof(unsigned short)); // 6.4 MB
    unsigned short* z1 = (unsigned short*)alloc((size_t)n * NCLS * sizeof(unsigned short)); // 6.4 MB

    dim3 blk(256);
    dim3 gB1((E + 256 * T1 - 1) / (256 * T1));   // 391
    dim3 gRow((n + 3) / 4);
    dim3 gTile((n + 63) / 64);

    zero_kernel<<<1, 256, 0, stream>>>(bcur, nb);
    bucket_kernel<<<gB1, blk, 0, stream>>>((const int2*)Aidx, bcur, bpack, E);
    csr_kernel<<<nb, blk, 0, stream>>>(bcur, bpack, csr, rowinfo, n);
    proj_kernel<<<gTile, blk, 0, stream>>>(X, W, rowinfo, xp, n);

    spmm_kernel<0><<<gRow, blk, 0, stream>>>((const ushort4*)xp, rowinfo, csr, bias, z1, n);
    spmm_kernel<1><<<gRow, blk, 0, stream>>>((const ushort4*)z1, rowinfo, csr, bias, out, n);
}